// Round 1
// baseline (305.567 us; speedup 1.0000x reference)
//
#include <hip/hip_runtime.h>

#define N    4096
#define SIZE 128
#define CAP  128   // max stored neighbors per row (mean ~21, 9+ sigma headroom)
#define RB   4     // output rows per block
#define TB   1024  // threads per block (fused kernel)
#define JITER (N / TB)  // 4

// ---- kernel A: build padded transposed CSR of `neighbors` ----
// idxT[c*N + j] = c-th nonzero column of row j; cnt[j] = nnz(row j)
__global__ __launch_bounds__(256)
void build_csr(const float* __restrict__ nb, int* __restrict__ cnt,
               int* __restrict__ idxT) {
    __shared__ int sc;
    const int j = blockIdx.x;
    if (threadIdx.x == 0) sc = 0;
    __syncthreads();
    const float* row = nb + (size_t)j * N;
    for (int c = threadIdx.x; c < N; c += 256) {
        if (row[c] != 0.0f) {
            int p = atomicAdd(&sc, 1);
            if (p < CAP) idxT[(size_t)p * N + j] = c;
        }
    }
    __syncthreads();
    if (threadIdx.x == 0) cnt[j] = (sc < CAP) ? sc : CAP;
}

// ---- kernel B: qwf[d*N+i] = wq[d]*wk[d]*f[d*N+i]  (wave-uniform scalar-load fodder) ----
__global__ __launch_bounds__(256)
void scale_f(const float* __restrict__ f, const float* __restrict__ wq,
             const float* __restrict__ wk, float* __restrict__ qwf) {
    int e = blockIdx.x * 256 + threadIdx.x;
    int d = e >> 12;  // e / N
    qwf[e] = wq[d] * wk[d] * f[e];
}

// ---- fused kernel: per block, RB rows i0..i0+3 of the output ----
// phase 1: s_r[j] = exp(sum_d qwf[d][i0+r] * f[d][j]) into LDS, layout sS[j] = {r0,r1,r2,r3}
// phase 2: out[i0+r][j] = s_r[j] / sum_{k in nbr(j)} s_r[k]
__global__ __launch_bounds__(TB)
void fused(const float* __restrict__ f, const float* __restrict__ qwf,
           const int* __restrict__ cnt, const int* __restrict__ idxT,
           float* __restrict__ out) {
    __shared__ float4 sS[N];  // 64 KB: one 16B chunk per column j (4 rows interleaved)
    const int t  = threadIdx.x;
    const int i0 = blockIdx.x * RB;

    // ---- phase 1: gram GEMM + exp ----
    float acc[JITER][RB];
#pragma unroll
    for (int u = 0; u < JITER; ++u)
#pragma unroll
        for (int r = 0; r < RB; ++r) acc[u][r] = 0.0f;

    for (int d = 0; d < SIZE; ++d) {
        const float* frow = f   + (size_t)d * N;
        const float* qrow = qwf + (size_t)d * N + i0;
        // wave-uniform addresses -> scalar loads
        const float q0 = qrow[0], q1 = qrow[1], q2 = qrow[2], q3 = qrow[3];
#pragma unroll
        for (int u = 0; u < JITER; ++u) {
            const float v = frow[t + u * TB];
            acc[u][0] = fmaf(q0, v, acc[u][0]);
            acc[u][1] = fmaf(q1, v, acc[u][1]);
            acc[u][2] = fmaf(q2, v, acc[u][2]);
            acc[u][3] = fmaf(q3, v, acc[u][3]);
        }
    }
#pragma unroll
    for (int u = 0; u < JITER; ++u) {
        const int j = t + u * TB;
        sS[j] = make_float4(__expf(acc[u][0]), __expf(acc[u][1]),
                            __expf(acc[u][2]), __expf(acc[u][3]));
    }
    __syncthreads();

    // ---- phase 2: sparse denominator gather + normalize + store ----
    for (int u = 0; u < JITER; ++u) {
        const int j = t + u * TB;
        const int c_end = cnt[j];
        float4 den = make_float4(0.f, 0.f, 0.f, 0.f);
        for (int c = 0; c < c_end; ++c) {
            const int k = idxT[(size_t)c * N + j];  // coalesced across lanes
            const float4 s = sS[k];                 // random-bank ds_read_b128
            den.x += s.x; den.y += s.y; den.z += s.z; den.w += s.w;
        }
        const float4 num = sS[j];
        out[(size_t)(i0 + 0) * N + j] = num.x / den.x;
        out[(size_t)(i0 + 1) * N + j] = num.y / den.y;
        out[(size_t)(i0 + 2) * N + j] = num.z / den.z;
        out[(size_t)(i0 + 3) * N + j] = num.w / den.w;
    }
}

extern "C" void kernel_launch(void* const* d_in, const int* in_sizes, int n_in,
                              void* d_out, int out_size, void* d_ws, size_t ws_size,
                              hipStream_t stream) {
    const float* f  = (const float*)d_in[0];   // [SIZE, N]
    const float* nb = (const float*)d_in[1];   // [N, N]
    const float* wq = (const float*)d_in[2];   // [SIZE]
    const float* wk = (const float*)d_in[3];   // [SIZE]
    float* out = (float*)d_out;                // [N, N]

    // workspace layout: cnt (N ints) | idxT (CAP*N ints) | qwf (SIZE*N floats) ~= 4.2 MB
    int*   cnt  = (int*)d_ws;
    int*   idxT = cnt + N;
    float* qwf  = (float*)(idxT + (size_t)CAP * N);

    build_csr<<<N, 256, 0, stream>>>(nb, cnt, idxT);
    scale_f<<<(SIZE * N) / 256, 256, 0, stream>>>(f, wq, wk, qwf);
    fused<<<N / RB, TB, 0, stream>>>(f, qwf, cnt, idxT, out);
}

// Round 2
// 255.251 us; speedup vs baseline: 1.1971x; 1.1971x over previous
//
#include <hip/hip_runtime.h>

#define N    4096
#define SIZE 128
#define CAP  128   // max stored neighbors per row (mean ~21.5, huge headroom), multiple of 4
#define RB   4     // output rows per block
#define TB   1024  // threads per block (fused kernel)
#define JITER (N / TB)  // 4

// ---- kernel A: build row-major padded adjacency index of `neighbors` ----
// idx[j*CAP + c] = c-th nonzero column of row j (order irrelevant: summed).
// Rows padded with sentinel N to a multiple of 4; cnt4[j] = padded_count/4.
__global__ __launch_bounds__(256)
void build_csr(const float* __restrict__ nb, int* __restrict__ cnt4,
               int* __restrict__ idx) {
    __shared__ int sc;
    const int j = blockIdx.x;
    if (threadIdx.x == 0) sc = 0;
    __syncthreads();
    const float4* row = (const float4*)(nb + (size_t)j * N);
    int* irow = idx + (size_t)j * CAP;
    for (int c = threadIdx.x; c < N / 4; c += 256) {
        const float4 v = row[c];
        if (v.x != 0.0f) { int p = atomicAdd(&sc, 1); if (p < CAP) irow[p] = 4 * c + 0; }
        if (v.y != 0.0f) { int p = atomicAdd(&sc, 1); if (p < CAP) irow[p] = 4 * c + 1; }
        if (v.z != 0.0f) { int p = atomicAdd(&sc, 1); if (p < CAP) irow[p] = 4 * c + 2; }
        if (v.w != 0.0f) { int p = atomicAdd(&sc, 1); if (p < CAP) irow[p] = 4 * c + 3; }
    }
    __syncthreads();
    if (threadIdx.x == 0) {
        int n = (sc < CAP) ? sc : CAP;
        int n4 = (n + 3) & ~3;
        for (int p = n; p < n4; ++p) irow[p] = N;  // sentinel -> zero LDS slot
        cnt4[j] = n4 >> 2;
    }
}

// ---- fused kernel: per block, RB rows i0..i0+3 of the output ----
// phase 1: s_r[j] = exp(sum_d q_r[d] * f[d][j]) into LDS, sS[j] = {r0,r1,r2,r3}
// phase 2: out[i0+r][j] = s_r[j] / sum_{k in nbr(j)} s_r[k]   (S symmetric)
__global__ __launch_bounds__(TB)
void fused(const float* __restrict__ f, const float* __restrict__ wq,
           const float* __restrict__ wk, const int* __restrict__ cnt4,
           const int* __restrict__ idx, float* __restrict__ out) {
    __shared__ float4 sS[N + 1];  // +1: zero slot for sentinel index N
    const int t  = threadIdx.x;
    const int i0 = blockIdx.x * RB;

    // ---- phase 1: gram GEMM + exp; j = 4*t + u ----
    float acc[4][RB];
#pragma unroll
    for (int u = 0; u < 4; ++u)
#pragma unroll
        for (int r = 0; r < RB; ++r) acc[u][r] = 0.0f;

    for (int d = 0; d < SIZE; ++d) {
        const float* frow = f + (size_t)d * N;
        const float  w    = wq[d] * wk[d];             // wave-uniform scalar
        const float q0 = w * frow[i0 + 0];
        const float q1 = w * frow[i0 + 1];
        const float q2 = w * frow[i0 + 2];
        const float q3 = w * frow[i0 + 3];
        const float4 v = ((const float4*)frow)[t];     // j = 4t..4t+3 coalesced 16B
        acc[0][0] = fmaf(q0, v.x, acc[0][0]);
        acc[0][1] = fmaf(q1, v.x, acc[0][1]);
        acc[0][2] = fmaf(q2, v.x, acc[0][2]);
        acc[0][3] = fmaf(q3, v.x, acc[0][3]);
        acc[1][0] = fmaf(q0, v.y, acc[1][0]);
        acc[1][1] = fmaf(q1, v.y, acc[1][1]);
        acc[1][2] = fmaf(q2, v.y, acc[1][2]);
        acc[1][3] = fmaf(q3, v.y, acc[1][3]);
        acc[2][0] = fmaf(q0, v.z, acc[2][0]);
        acc[2][1] = fmaf(q1, v.z, acc[2][1]);
        acc[2][2] = fmaf(q2, v.z, acc[2][2]);
        acc[2][3] = fmaf(q3, v.z, acc[2][3]);
        acc[3][0] = fmaf(q0, v.w, acc[3][0]);
        acc[3][1] = fmaf(q1, v.w, acc[3][1]);
        acc[3][2] = fmaf(q2, v.w, acc[3][2]);
        acc[3][3] = fmaf(q3, v.w, acc[3][3]);
    }
#pragma unroll
    for (int u = 0; u < 4; ++u) {
        sS[4 * t + u] = make_float4(__expf(acc[u][0]), __expf(acc[u][1]),
                                    __expf(acc[u][2]), __expf(acc[u][3]));
    }
    if (t == 0) sS[N] = make_float4(0.f, 0.f, 0.f, 0.f);
    __syncthreads();

    // ---- phase 2: sparse denominator gather (4 indices/iter for ILP) ----
    for (int u = 0; u < JITER; ++u) {
        const int j  = t + u * TB;
        const int c4 = cnt4[j];
        const int4* irow = (const int4*)(idx + (size_t)j * CAP);
        float4 den = make_float4(0.f, 0.f, 0.f, 0.f);
        for (int c = 0; c < c4; ++c) {
            const int4 k = irow[c];          // 4 indices in one 16B load
            const float4 a = sS[k.x];        // 4 independent ds_read_b128
            const float4 b = sS[k.y];
            const float4 g = sS[k.z];
            const float4 h = sS[k.w];
            den.x += (a.x + b.x) + (g.x + h.x);
            den.y += (a.y + b.y) + (g.y + h.y);
            den.z += (a.z + b.z) + (g.z + h.z);
            den.w += (a.w + b.w) + (g.w + h.w);
        }
        const float4 num = sS[j];
        out[(size_t)(i0 + 0) * N + j] = num.x / den.x;
        out[(size_t)(i0 + 1) * N + j] = num.y / den.y;
        out[(size_t)(i0 + 2) * N + j] = num.z / den.z;
        out[(size_t)(i0 + 3) * N + j] = num.w / den.w;
    }
}

extern "C" void kernel_launch(void* const* d_in, const int* in_sizes, int n_in,
                              void* d_out, int out_size, void* d_ws, size_t ws_size,
                              hipStream_t stream) {
    const float* f  = (const float*)d_in[0];   // [SIZE, N]
    const float* nb = (const float*)d_in[1];   // [N, N]
    const float* wq = (const float*)d_in[2];   // [SIZE]
    const float* wk = (const float*)d_in[3];   // [SIZE]
    float* out = (float*)d_out;                // [N, N]

    // workspace: cnt4 (N ints) | idx (N*CAP ints) ~= 2.1 MB
    int* cnt4 = (int*)d_ws;
    int* idx  = cnt4 + N;

    build_csr<<<N, 256, 0, stream>>>(nb, cnt4, idx);
    fused<<<N / RB, TB, 0, stream>>>(f, wq, wk, cnt4, idx, out);
}

// Round 3
// 247.459 us; speedup vs baseline: 1.2348x; 1.0315x over previous
//
#include <hip/hip_runtime.h>

#define N    4096
#define SIZE 128
#define CAP  128   // max stored neighbors per row (mean ~21.5), multiple of 4
#define RB   8     // output rows per block
#define TB   1024  // threads per block (fused kernel)
#define JITER (N / TB)  // 4

// ---- bf16 helpers (manual RNE pack / shift unpack) ----
__device__ __forceinline__ unsigned int bf16rne(float x) {
    union { float f; unsigned int u; } c; c.f = x;
    return (c.u + 0x7fffu + ((c.u >> 16) & 1u)) >> 16;
}
__device__ __forceinline__ float bflo(unsigned int u) {
    union { unsigned int u; float f; } c; c.u = u << 16; return c.f;
}
__device__ __forceinline__ float bfhi(unsigned int u) {
    union { unsigned int u; float f; } c; c.u = u & 0xffff0000u; return c.f;
}

// ---- kernel A: build row-major padded adjacency index via ballot compaction ----
// idx[j*CAP + c] = c-th nonzero column of row j (order irrelevant: summed).
// One atomic per wave per 64 elements instead of one per nonzero element;
// all 4 float4 loads hoisted before the ballot chain for MLP.
__global__ __launch_bounds__(256)
void build_csr(const float* __restrict__ nb, int* __restrict__ cnt4,
               int* __restrict__ idx) {
    __shared__ int sc;
    const int j    = blockIdx.x;
    const int lane = threadIdx.x & 63;
    if (threadIdx.x == 0) sc = 0;
    __syncthreads();
    const float4* row4 = (const float4*)(nb + (size_t)j * N);
    int* irow = idx + (size_t)j * CAP;

    float4 v[4];
#pragma unroll
    for (int it = 0; it < 4; ++it) v[it] = row4[threadIdx.x + it * 256];

#pragma unroll
    for (int it = 0; it < 4; ++it) {
        const float e[4] = {v[it].x, v[it].y, v[it].z, v[it].w};
#pragma unroll
        for (int q = 0; q < 4; ++q) {
            const bool nz = (e[q] != 0.0f);
            const unsigned long long m = __ballot(nz);
            if (m != 0ull) {
                int base = 0;
                if (lane == 0) base = atomicAdd(&sc, __popcll(m));
                base = __shfl(base, 0);
                if (nz) {
                    const int p = base + __popcll(m & ((1ull << lane) - 1ull));
                    const int c = 4 * (threadIdx.x + it * 256) + q;
                    if (p < CAP) irow[p] = c;
                }
            }
        }
    }
    __syncthreads();
    if (threadIdx.x == 0) {
        int n  = (sc < CAP) ? sc : CAP;
        int n4 = (n + 3) & ~3;
        for (int p = n; p < n4; ++p) irow[p] = N;  // sentinel -> zero LDS slot
        cnt4[j] = n4 >> 2;
    }
}

// ---- fused kernel: per block, RB=8 rows i0..i0+7 of the output ----
// phase 1: s_r[j] = exp(sum_d q_r[d] * f[d][j]), packed bf16 x8 into sS[j] (uint4)
// phase 2: out[i0+r][j] = s_r[j] / sum_{k in nbr(j)} s_r[k]   (S symmetric)
__global__ __launch_bounds__(TB, 8)
void fused(const float* __restrict__ f, const float* __restrict__ wq,
           const float* __restrict__ wk, const int* __restrict__ cnt4,
           const int* __restrict__ idx, float* __restrict__ out) {
    __shared__ uint4 sS[N + 1];  // 64 KB + 16 B: 8 bf16 rows per column j
    const int t  = threadIdx.x;
    const int i0 = blockIdx.x * RB;

    // ---- phase 1: gram GEMM + exp; j = 4*t + u ----
    float acc[4][RB];
#pragma unroll
    for (int u = 0; u < 4; ++u)
#pragma unroll
        for (int r = 0; r < RB; ++r) acc[u][r] = 0.0f;

    for (int d = 0; d < SIZE; ++d) {
        const float* frow = f + (size_t)d * N;
        const float  w    = wq[d] * wk[d];
        float q[RB];
#pragma unroll
        for (int r = 0; r < RB; ++r) q[r] = w * frow[i0 + r];  // wave-uniform scalar loads
        const float4 v = ((const float4*)frow)[t];             // j = 4t..4t+3, 16B coalesced
        const float vv[4] = {v.x, v.y, v.z, v.w};
#pragma unroll
        for (int u = 0; u < 4; ++u)
#pragma unroll
            for (int r = 0; r < RB; ++r)
                acc[u][r] = fmaf(q[r], vv[u], acc[u][r]);
    }
#pragma unroll
    for (int u = 0; u < 4; ++u) {
        uint4 p;
        p.x = bf16rne(__expf(acc[u][0])) | (bf16rne(__expf(acc[u][1])) << 16);
        p.y = bf16rne(__expf(acc[u][2])) | (bf16rne(__expf(acc[u][3])) << 16);
        p.z = bf16rne(__expf(acc[u][4])) | (bf16rne(__expf(acc[u][5])) << 16);
        p.w = bf16rne(__expf(acc[u][6])) | (bf16rne(__expf(acc[u][7])) << 16);
        sS[4 * t + u] = p;
    }
    if (t == 0) sS[N] = make_uint4(0u, 0u, 0u, 0u);
    __syncthreads();

    // ---- phase 2: sparse denominator gather (4 indices/iter, 1-ahead prefetch) ----
    for (int u = 0; u < JITER; ++u) {
        const int j  = t + u * TB;
        const int c4 = cnt4[j];
        const int4* irow = (const int4*)(idx + (size_t)j * CAP);
        float den[RB];
#pragma unroll
        for (int r = 0; r < RB; ++r) den[r] = 0.0f;

        int4 k = irow[0];
        for (int c = 0; c < c4; ++c) {
            const int4 kn = (c + 1 < c4) ? irow[c + 1] : k;
            const uint4 a = sS[k.x];
            const uint4 b = sS[k.y];
            const uint4 g = sS[k.z];
            const uint4 h = sS[k.w];
            den[0] += bflo(a.x) + bflo(b.x) + bflo(g.x) + bflo(h.x);
            den[1] += bfhi(a.x) + bfhi(b.x) + bfhi(g.x) + bfhi(h.x);
            den[2] += bflo(a.y) + bflo(b.y) + bflo(g.y) + bflo(h.y);
            den[3] += bfhi(a.y) + bfhi(b.y) + bfhi(g.y) + bfhi(h.y);
            den[4] += bflo(a.z) + bflo(b.z) + bflo(g.z) + bflo(h.z);
            den[5] += bfhi(a.z) + bfhi(b.z) + bfhi(g.z) + bfhi(h.z);
            den[6] += bflo(a.w) + bflo(b.w) + bflo(g.w) + bflo(h.w);
            den[7] += bfhi(a.w) + bfhi(b.w) + bfhi(g.w) + bfhi(h.w);
            k = kn;
        }
        const uint4 num = sS[j];
        const float nums[RB] = {bflo(num.x), bfhi(num.x), bflo(num.y), bfhi(num.y),
                                bflo(num.z), bfhi(num.z), bflo(num.w), bfhi(num.w)};
#pragma unroll
        for (int r = 0; r < RB; ++r)
            out[(size_t)(i0 + r) * N + j] = nums[r] * __builtin_amdgcn_rcpf(den[r]);
    }
}

extern "C" void kernel_launch(void* const* d_in, const int* in_sizes, int n_in,
                              void* d_out, int out_size, void* d_ws, size_t ws_size,
                              hipStream_t stream) {
    const float* f  = (const float*)d_in[0];   // [SIZE, N]
    const float* nb = (const float*)d_in[1];   // [N, N]
    const float* wq = (const float*)d_in[2];   // [SIZE]
    const float* wk = (const float*)d_in[3];   // [SIZE]
    float* out = (float*)d_out;                // [N, N]

    // workspace: cnt4 (N ints) | idx (N*CAP ints) ~= 2.1 MB
    int* cnt4 = (int*)d_ws;
    int* idx  = cnt4 + N;

    build_csr<<<N, 256, 0, stream>>>(nb, cnt4, idx);
    fused<<<N / RB, TB, 0, stream>>>(f, wq, wk, cnt4, idx, out);
}

// Round 4
// 169.503 us; speedup vs baseline: 1.8027x; 1.4599x over previous
//
#include <hip/hip_runtime.h>

#define N    4096
#define SIZE 128
#define CAP  128   // max stored neighbors per row (mean ~21.5), multiple of 4
#define RB   16    // output rows per block (one 16-row MFMA M-tile)
#define TB   1024  // threads per block (fused kernel)

typedef __attribute__((ext_vector_type(8))) short bf16x8;  // MFMA A/B frag (4 VGPRs)
typedef __attribute__((ext_vector_type(4))) float f32x4;   // MFMA C/D frag

// ---- bf16 helpers (manual RNE pack / shift unpack) ----
__device__ __forceinline__ unsigned int bf16rne(float x) {
    union { float f; unsigned int u; } c; c.f = x;
    return (c.u + 0x7fffu + ((c.u >> 16) & 1u)) >> 16;
}
__device__ __forceinline__ short bf16s(float x) { return (short)bf16rne(x); }
__device__ __forceinline__ float bflo(unsigned int u) {
    union { unsigned int u; float f; } c; c.u = u << 16; return c.f;
}
__device__ __forceinline__ float bfhi(unsigned int u) {
    union { unsigned int u; float f; } c; c.u = u & 0xffff0000u; return c.f;
}

// ---- kernel A: build row-major padded adjacency index via ballot compaction ----
__global__ __launch_bounds__(256)
void build_csr(const float* __restrict__ nb, int* __restrict__ cnt4,
               int* __restrict__ idx) {
    __shared__ int sc;
    const int j    = blockIdx.x;
    const int lane = threadIdx.x & 63;
    if (threadIdx.x == 0) sc = 0;
    __syncthreads();
    const float4* row4 = (const float4*)(nb + (size_t)j * N);
    int* irow = idx + (size_t)j * CAP;

    float4 v[4];
#pragma unroll
    for (int it = 0; it < 4; ++it) v[it] = row4[threadIdx.x + it * 256];

#pragma unroll
    for (int it = 0; it < 4; ++it) {
        const float e[4] = {v[it].x, v[it].y, v[it].z, v[it].w};
#pragma unroll
        for (int q = 0; q < 4; ++q) {
            const bool nz = (e[q] != 0.0f);
            const unsigned long long m = __ballot(nz);
            if (m != 0ull) {
                int base = 0;
                if (lane == 0) base = atomicAdd(&sc, __popcll(m));
                base = __shfl(base, 0);
                if (nz) {
                    const int p = base + __popcll(m & ((1ull << lane) - 1ull));
                    const int c = 4 * (threadIdx.x + it * 256) + q;
                    if (p < CAP) irow[p] = c;
                }
            }
        }
    }
    __syncthreads();
    if (threadIdx.x == 0) {
        int n  = (sc < CAP) ? sc : CAP;
        int n4 = (n + 3) & ~3;
        for (int p = n; p < n4; ++p) irow[p] = N;  // sentinel -> zero LDS slot
        cnt4[j] = n4 >> 2;
    }
}

// ---- kernel B: swizzle f into MFMA fragment order (bf16) ----
// A table (half 0): qwfA[(tile*4+ks)*64 + lane][jj] = bf16(wq[k]*wk[k]*f[k][tile*16 + (lane&15)])
// B table (half 1): fB  [(tile*4+ks)*64 + lane][jj] = bf16(               f[k][tile*16 + (lane&15)])
// with k = ks*32 + (lane>>4)*8 + jj  -- exactly the 16x16x32 bf16 A/B lane layout.
__global__ __launch_bounds__(256)
void prep(const float* __restrict__ f, const float* __restrict__ wq,
          const float* __restrict__ wk, short* __restrict__ qwfA,
          short* __restrict__ fB) {
    const int tid  = blockIdx.x * 256 + threadIdx.x;  // [0, 131072)
    const int half = tid >> 16;
    const int id   = tid & 65535;
    const int grp  = id >> 6;       // tile*4 + ks
    const int lane = id & 63;
    const int tile = grp >> 2;
    const int ks   = grp & 3;
    const int quad = lane >> 4;
    const int col  = lane & 15;
    bf16x8 v;
    if (half == 0) {
#pragma unroll
        for (int jj = 0; jj < 8; ++jj) {
            const int k = ks * 32 + quad * 8 + jj;
            v[jj] = bf16s(wq[k] * wk[k] * f[(size_t)k * N + tile * 16 + col]);
        }
        ((bf16x8*)qwfA)[id] = v;
    } else {
#pragma unroll
        for (int jj = 0; jj < 8; ++jj) {
            const int k = ks * 32 + quad * 8 + jj;
            v[jj] = bf16s(f[(size_t)k * N + tile * 16 + col]);
        }
        ((bf16x8*)fB)[id] = v;
    }
}

// ---- fused kernel: 16 output rows per block via MFMA ----
// phase 1: G[i0+m][j] = sum_k qwf[k][i0+m] * f[k][j] via 16x16x32 bf16 MFMA,
//          s = exp(G) packed bf16 into sA (rows 0-7) / sB (rows 8-15) per column j
// phase 2: out[i0+r][j] = s_r[j] / sum_{k in nbr(j)} s_r[k]   (S symmetric)
__global__ __launch_bounds__(TB, 4)
void fused(const short* __restrict__ qwfA, const short* __restrict__ fB,
           const int* __restrict__ cnt4, const int* __restrict__ idx,
           float* __restrict__ out) {
    __shared__ uint4 sA[N + 1];   // rows 0-7  (8 bf16 per column), +1 zero slot
    __shared__ uint4 sB[N + 1];   // rows 8-15
    const int t    = threadIdx.x;
    const int lane = t & 63;
    const int wv   = t >> 6;      // wave 0..15
    const int quad = lane >> 4;
    const int i0   = blockIdx.x * RB;

    // ---- phase 1 ----
    bf16x8 af[4];
    const bf16x8* Ap = (const bf16x8*)qwfA + (size_t)blockIdx.x * 4 * 64;
#pragma unroll
    for (int ks = 0; ks < 4; ++ks) af[ks] = Ap[ks * 64 + lane];
    const bf16x8* Bp = (const bf16x8*)fB;

#pragma unroll 4
    for (int ti = 0; ti < 16; ++ti) {
        const int nt = wv * 16 + ti;          // column tile: j = nt*16 .. nt*16+15
        f32x4 acc = {0.f, 0.f, 0.f, 0.f};
#pragma unroll
        for (int ks = 0; ks < 4; ++ks) {
            const bf16x8 bfrag = Bp[(size_t)(nt * 4 + ks) * 64 + lane];
            acc = __builtin_amdgcn_mfma_f32_16x16x32_bf16(af[ks], bfrag, acc, 0, 0, 0);
        }
        // C/D: col = lane&15, row = quad*4 + reg
        const int j = nt * 16 + (lane & 15);
        uint2 p;
        p.x = bf16rne(__expf(acc[0])) | (bf16rne(__expf(acc[1])) << 16);
        p.y = bf16rne(__expf(acc[2])) | (bf16rne(__expf(acc[3])) << 16);
        uint2* base = (quad < 2) ? (uint2*)&sA[j] : (uint2*)&sB[j];
        base[quad & 1] = p;
    }
    if (t == 0) {
        sA[N] = make_uint4(0u, 0u, 0u, 0u);
        sB[N] = make_uint4(0u, 0u, 0u, 0u);
    }
    __syncthreads();

    // ---- phase 2: sparse denominator gather ----
    for (int u = 0; u < N / TB; ++u) {
        const int j  = t + u * TB;
        const int c4 = cnt4[j];
        const int4* irow = (const int4*)(idx + (size_t)j * CAP);
        float den[RB];
#pragma unroll
        for (int r = 0; r < RB; ++r) den[r] = 0.0f;

        int4 k = irow[0];
        for (int c = 0; c < c4; ++c) {
            const int4 kn = (c + 1 < c4) ? irow[c + 1] : k;
            const uint4 a0 = sA[k.x], b0 = sB[k.x];
            const uint4 a1 = sA[k.y], b1 = sB[k.y];
            const uint4 a2 = sA[k.z], b2 = sB[k.z];
            const uint4 a3 = sA[k.w], b3 = sB[k.w];
            den[0]  += bflo(a0.x) + bflo(a1.x) + bflo(a2.x) + bflo(a3.x);
            den[1]  += bfhi(a0.x) + bfhi(a1.x) + bfhi(a2.x) + bfhi(a3.x);
            den[2]  += bflo(a0.y) + bflo(a1.y) + bflo(a2.y) + bflo(a3.y);
            den[3]  += bfhi(a0.y) + bfhi(a1.y) + bfhi(a2.y) + bfhi(a3.y);
            den[4]  += bflo(a0.z) + bflo(a1.z) + bflo(a2.z) + bflo(a3.z);
            den[5]  += bfhi(a0.z) + bfhi(a1.z) + bfhi(a2.z) + bfhi(a3.z);
            den[6]  += bflo(a0.w) + bflo(a1.w) + bflo(a2.w) + bflo(a3.w);
            den[7]  += bfhi(a0.w) + bfhi(a1.w) + bfhi(a2.w) + bfhi(a3.w);
            den[8]  += bflo(b0.x) + bflo(b1.x) + bflo(b2.x) + bflo(b3.x);
            den[9]  += bfhi(b0.x) + bfhi(b1.x) + bfhi(b2.x) + bfhi(b3.x);
            den[10] += bflo(b0.y) + bflo(b1.y) + bflo(b2.y) + bflo(b3.y);
            den[11] += bfhi(b0.y) + bfhi(b1.y) + bfhi(b2.y) + bfhi(b3.y);
            den[12] += bflo(b0.z) + bflo(b1.z) + bflo(b2.z) + bflo(b3.z);
            den[13] += bfhi(b0.z) + bfhi(b1.z) + bfhi(b2.z) + bfhi(b3.z);
            den[14] += bflo(b0.w) + bflo(b1.w) + bflo(b2.w) + bflo(b3.w);
            den[15] += bfhi(b0.w) + bfhi(b1.w) + bfhi(b2.w) + bfhi(b3.w);
            k = kn;
        }
        const uint4 na = sA[j], nb = sB[j];
        const float nums[RB] = {
            bflo(na.x), bfhi(na.x), bflo(na.y), bfhi(na.y),
            bflo(na.z), bfhi(na.z), bflo(na.w), bfhi(na.w),
            bflo(nb.x), bfhi(nb.x), bflo(nb.y), bfhi(nb.y),
            bflo(nb.z), bfhi(nb.z), bflo(nb.w), bfhi(nb.w)};
#pragma unroll
        for (int r = 0; r < RB; ++r)
            out[(size_t)(i0 + r) * N + j] = nums[r] * __builtin_amdgcn_rcpf(den[r]);
    }
}

extern "C" void kernel_launch(void* const* d_in, const int* in_sizes, int n_in,
                              void* d_out, int out_size, void* d_ws, size_t ws_size,
                              hipStream_t stream) {
    const float* f  = (const float*)d_in[0];   // [SIZE, N]
    const float* nb = (const float*)d_in[1];   // [N, N]
    const float* wq = (const float*)d_in[2];   // [SIZE]
    const float* wk = (const float*)d_in[3];   // [SIZE]
    float* out = (float*)d_out;                // [N, N]

    // workspace: cnt4 (N int) | idx (N*CAP int) | qwfA (512K shorts) | fB (512K shorts) ~= 4.1 MB
    int*   cnt4 = (int*)d_ws;
    int*   idx  = cnt4 + N;
    short* qwfA = (short*)(idx + (size_t)N * CAP);
    short* fB   = qwfA + (size_t)256 * 4 * 64 * 8;

    prep<<<512, 256, 0, stream>>>(f, wq, wk, qwfA, fB);
    build_csr<<<N, 256, 0, stream>>>(nb, cnt4, idx);
    fused<<<N / RB, TB, 0, stream>>>(qwfA, fB, cnt4, idx, out);
}

// Round 6
// 168.023 us; speedup vs baseline: 1.8186x; 1.0088x over previous
//
#include <hip/hip_runtime.h>
#include <hip/hip_fp16.h>

#define N    4096
#define SIZE 128
#define CAP  128   // max stored neighbors per row (mean ~21.5), multiple of 4
#define RB   16    // output rows per block (one 16-row MFMA M-tile)
#define TB   1024  // threads per block (fused kernel)

typedef __attribute__((ext_vector_type(8))) _Float16 f16x8;  // MFMA A/B frag (4 VGPRs)
typedef __attribute__((ext_vector_type(2))) __fp16 fp16x2;   // cvt_pkrtz return type
typedef __attribute__((ext_vector_type(4))) float f32x4;     // MFMA C/D frag

__device__ __forceinline__ unsigned int pk2(float lo, float hi) {
    union { fp16x2 v; unsigned int u; } c;
    c.v = __builtin_amdgcn_cvt_pkrtz(lo, hi);   // 1 instr, RTZ
    return c.u;
}
__device__ __forceinline__ __half2 u2h(unsigned int u) {
    union { unsigned int u; __half2 h; } c; c.u = u; return c.h;
}

// ---- kernel A: build row-major padded adjacency index via ballot compaction ----
__global__ __launch_bounds__(256)
void build_csr(const float* __restrict__ nb, int* __restrict__ cnt4,
               int* __restrict__ idx) {
    __shared__ int sc;
    const int j    = blockIdx.x;
    const int lane = threadIdx.x & 63;
    if (threadIdx.x == 0) sc = 0;
    __syncthreads();
    const float4* row4 = (const float4*)(nb + (size_t)j * N);
    int* irow = idx + (size_t)j * CAP;

    float4 v[4];
#pragma unroll
    for (int it = 0; it < 4; ++it) v[it] = row4[threadIdx.x + it * 256];

#pragma unroll
    for (int it = 0; it < 4; ++it) {
        const float e[4] = {v[it].x, v[it].y, v[it].z, v[it].w};
#pragma unroll
        for (int q = 0; q < 4; ++q) {
            const bool nz = (e[q] != 0.0f);
            const unsigned long long m = __ballot(nz);
            if (m != 0ull) {
                int base = 0;
                if (lane == 0) base = atomicAdd(&sc, __popcll(m));
                base = __shfl(base, 0);
                if (nz) {
                    const int p = base + __popcll(m & ((1ull << lane) - 1ull));
                    const int c = 4 * (threadIdx.x + it * 256) + q;
                    if (p < CAP) irow[p] = c;
                }
            }
        }
    }
    __syncthreads();
    if (threadIdx.x == 0) {
        int n  = (sc < CAP) ? sc : CAP;
        int n4 = (n + 3) & ~3;
        for (int p = n; p < n4; ++p) irow[p] = N;  // sentinel -> zero LDS slot
        cnt4[j] = n4 >> 2;
    }
}

// ---- kernel B: swizzle f into f16 MFMA fragment order, LDS-staged ----
// One block per 16-column tile. A[(tile*4+ks)*64+lane][jj] = f16(wq[k]wk[k]f[k][tile*16+col]),
// B likewise without the scale; k = ks*32 + (lane>>4)*8 + jj, col = lane&15
// (identical lane mapping verified correct in round 4 with bf16).
__global__ __launch_bounds__(256)
void prep(const float* __restrict__ f, const float* __restrict__ wq,
          const float* __restrict__ wk, _Float16* __restrict__ Af,
          _Float16* __restrict__ Bf) {
    __shared__ float sf[SIZE][16];
    __shared__ float sqw[SIZE];
    const int t    = threadIdx.x;
    const int tile = blockIdx.x;
    if (t < SIZE) sqw[t] = wq[t] * wk[t];
    const int col0 = t & 15;
#pragma unroll
    for (int it = 0; it < 8; ++it) {
        const int k = (t >> 4) + it * 16;
        sf[k][col0] = f[(size_t)k * N + tile * 16 + col0];  // 64B coalesced per 16 lanes
    }
    __syncthreads();

    const int ks   = t >> 6;
    const int lane = t & 63;
    const int quad = lane >> 4;
    const int col  = lane & 15;
    f16x8 va, vb;
#pragma unroll
    for (int jj = 0; jj < 8; ++jj) {
        const int k = ks * 32 + quad * 8 + jj;
        const float v = sf[k][col];
        va[jj] = (_Float16)(sqw[k] * v);
        vb[jj] = (_Float16)v;
    }
    const size_t o = (size_t)(tile * 4 + ks) * 64 + lane;
    ((f16x8*)Af)[o] = va;
    ((f16x8*)Bf)[o] = vb;
}

// ---- fused kernel: 16 output rows per block via f16 MFMA + packed-f16 gather ----
__global__ __launch_bounds__(TB, 4)
void fused(const _Float16* __restrict__ Af, const _Float16* __restrict__ Bf,
           const int* __restrict__ cnt4, const int* __restrict__ idx,
           float* __restrict__ out) {
    // sA: rows 0-7 (8 f16/column), sB: rows 8-15; sB offset +2 slots so the two
    // reads per neighbor land in different bank groups. +1 slot each = zero sentinel.
    __shared__ uint4 Sb[2 * N + 3];           // 131,120 B
    uint4* const sA = Sb;
    uint4* const sB = Sb + N + 2;
    const int t    = threadIdx.x;
    const int lane = t & 63;
    const int wv   = t >> 6;
    const int quad = lane >> 4;
    const int i0   = blockIdx.x * RB;

    // ---- phase 1 ----
    f16x8 af[4];
    const f16x8* Ap = (const f16x8*)Af + (size_t)blockIdx.x * 4 * 64;
#pragma unroll
    for (int ks = 0; ks < 4; ++ks) af[ks] = Ap[ks * 64 + lane];
    const f16x8* Bp = (const f16x8*)Bf;

#pragma unroll 4
    for (int ti = 0; ti < 16; ++ti) {
        const int nt = wv * 16 + ti;          // column tile: j = nt*16 .. nt*16+15
        f32x4 acc = {0.f, 0.f, 0.f, 0.f};
#pragma unroll
        for (int ks = 0; ks < 4; ++ks) {
            const f16x8 bfrag = Bp[(size_t)(nt * 4 + ks) * 64 + lane];
            acc = __builtin_amdgcn_mfma_f32_16x16x32_f16(af[ks], bfrag, acc, 0, 0, 0);
        }
        // C/D: col = lane&15, row = quad*4 + reg
        const int j = nt * 16 + (lane & 15);
        uint2 p;
        p.x = pk2(__expf(acc[0]), __expf(acc[1]));
        p.y = pk2(__expf(acc[2]), __expf(acc[3]));
        uint2* base = (quad < 2) ? (uint2*)&sA[j] : (uint2*)&sB[j];
        base[quad & 1] = p;
    }
    if (t == 0) {
        sA[N] = make_uint4(0u, 0u, 0u, 0u);
        sB[N] = make_uint4(0u, 0u, 0u, 0u);
    }
    __syncthreads();

    // ---- phase 2: sparse gather, packed-f16 accumulation (v_pk_add_f16) ----
    for (int u = 0; u < N / TB; ++u) {
        const int j  = t + u * TB;
        const int c4 = cnt4[j];
        const int4* irow = (const int4*)(idx + (size_t)j * CAP);
        __half2 d0[8], d1[8];                 // two independent sets (chain halved)
        const __half2 z = u2h(0u);
#pragma unroll
        for (int r = 0; r < 8; ++r) { d0[r] = z; d1[r] = z; }

        int4 k = irow[0];
        for (int c = 0; c < c4; ++c) {
            const int4 kn = (c + 1 < c4) ? irow[c + 1] : k;
            const uint4 ax = sA[k.x], bx = sB[k.x];
            const uint4 ay = sA[k.y], by = sB[k.y];
            const uint4 az = sA[k.z], bz = sB[k.z];
            const uint4 aw = sA[k.w], bw = sB[k.w];
            d0[0] = __hadd2(d0[0], u2h(ax.x)); d1[0] = __hadd2(d1[0], u2h(ay.x));
            d0[1] = __hadd2(d0[1], u2h(ax.y)); d1[1] = __hadd2(d1[1], u2h(ay.y));
            d0[2] = __hadd2(d0[2], u2h(ax.z)); d1[2] = __hadd2(d1[2], u2h(ay.z));
            d0[3] = __hadd2(d0[3], u2h(ax.w)); d1[3] = __hadd2(d1[3], u2h(ay.w));
            d0[4] = __hadd2(d0[4], u2h(bx.x)); d1[4] = __hadd2(d1[4], u2h(by.x));
            d0[5] = __hadd2(d0[5], u2h(bx.y)); d1[5] = __hadd2(d1[5], u2h(by.y));
            d0[6] = __hadd2(d0[6], u2h(bx.z)); d1[6] = __hadd2(d1[6], u2h(by.z));
            d0[7] = __hadd2(d0[7], u2h(bx.w)); d1[7] = __hadd2(d1[7], u2h(by.w));
            d0[0] = __hadd2(d0[0], u2h(az.x)); d1[0] = __hadd2(d1[0], u2h(aw.x));
            d0[1] = __hadd2(d0[1], u2h(az.y)); d1[1] = __hadd2(d1[1], u2h(aw.y));
            d0[2] = __hadd2(d0[2], u2h(az.z)); d1[2] = __hadd2(d1[2], u2h(aw.z));
            d0[3] = __hadd2(d0[3], u2h(az.w)); d1[3] = __hadd2(d1[3], u2h(aw.w));
            d0[4] = __hadd2(d0[4], u2h(bz.x)); d1[4] = __hadd2(d1[4], u2h(bw.x));
            d0[5] = __hadd2(d0[5], u2h(bz.y)); d1[5] = __hadd2(d1[5], u2h(bw.y));
            d0[6] = __hadd2(d0[6], u2h(bz.z)); d1[6] = __hadd2(d1[6], u2h(bw.z));
            d0[7] = __hadd2(d0[7], u2h(bz.w)); d1[7] = __hadd2(d1[7], u2h(bw.w));
            k = kn;
        }
        const uint4 na = sA[j], nb = sB[j];
        const unsigned int nu[8] = {na.x, na.y, na.z, na.w, nb.x, nb.y, nb.z, nb.w};
#pragma unroll
        for (int i = 0; i < 8; ++i) {
            const __half2 dd = __hadd2(d0[i], d1[i]);
            const __half2 nn = u2h(nu[i]);
            out[(size_t)(i0 + 2 * i + 0) * N + j] =
                __low2float(nn)  * __builtin_amdgcn_rcpf(__low2float(dd));
            out[(size_t)(i0 + 2 * i + 1) * N + j] =
                __high2float(nn) * __builtin_amdgcn_rcpf(__high2float(dd));
        }
    }
}

extern "C" void kernel_launch(void* const* d_in, const int* in_sizes, int n_in,
                              void* d_out, int out_size, void* d_ws, size_t ws_size,
                              hipStream_t stream) {
    const float* f  = (const float*)d_in[0];   // [SIZE, N]
    const float* nb = (const float*)d_in[1];   // [N, N]
    const float* wq = (const float*)d_in[2];   // [SIZE]
    const float* wk = (const float*)d_in[3];   // [SIZE]
    float* out = (float*)d_out;                // [N, N]

    // workspace: cnt4 (N int) | idx (N*CAP int) | Af (512K f16) | Bf (512K f16) ~= 4.1 MB
    int*      cnt4 = (int*)d_ws;
    int*      idx  = cnt4 + N;
    _Float16* Af   = (_Float16*)(idx + (size_t)N * CAP);
    _Float16* Bf   = Af + (size_t)256 * 4 * 64 * 8;

    build_csr<<<N, 256, 0, stream>>>(nb, cnt4, idx);
    prep<<<256, 256, 0, stream>>>(f, wq, wk, Af, Bf);
    fused<<<N / RB, TB, 0, stream>>>(Af, Bf, cnt4, idx, out);
}